// Round 1
// baseline (1164.359 us; speedup 1.0000x reference)
//
#include <hip/hip_runtime.h>

#define N_NODES 100000

// ---------------- histogram of dst ----------------
__global__ void hist_kernel(const int* __restrict__ dst, int* __restrict__ counts, int E) {
    int e = blockIdx.x * 256 + threadIdx.x;
    if (e < E) atomicAdd(&counts[dst[e]], 1);
}

// ---------------- single-block exclusive scan (wave-shuffle based) ----------------
__global__ void scan_kernel(const int* __restrict__ counts, int* __restrict__ offsets,
                            int* __restrict__ cursor) {
    const int tid  = threadIdx.x;          // 1024 threads
    const int lane = tid & 63;
    const int wave = tid >> 6;             // 16 waves
    __shared__ int wsum[16];
    __shared__ int carry;
    if (tid == 0) carry = 0;
    __syncthreads();
    for (int base = 0; base < N_NODES; base += 1024) {
        int i = base + tid;
        int v = (i < N_NODES) ? counts[i] : 0;
        // wave-inclusive scan
        int x = v;
        #pragma unroll
        for (int off = 1; off < 64; off <<= 1) {
            int t = __shfl_up(x, off, 64);
            if (lane >= off) x += t;
        }
        if (lane == 63) wsum[wave] = x;
        __syncthreads();
        int waveoff = 0, tot = 0;
        #pragma unroll
        for (int w = 0; w < 16; ++w) {
            int s = wsum[w];
            if (w < wave) waveoff += s;
            tot += s;
        }
        int excl = carry + waveoff + x - v;
        if (i < N_NODES) { offsets[i] = excl; cursor[i] = excl; }
        __syncthreads();
        if (tid == 0) carry += tot;
        __syncthreads();
    }
    if (tid == 0) offsets[N_NODES] = carry;
}

// ---------------- counting-sort placement ----------------
__global__ void fill_kernel(const int* __restrict__ src, const int* __restrict__ dst,
                            int* __restrict__ cursor, int* __restrict__ sorted_src, int E) {
    int e = blockIdx.x * 256 + threadIdx.x;
    if (e < E) {
        int p = atomicAdd(&cursor[dst[e]], 1);
        sorted_src[p] = src[e];
    }
}

// ---------------- pull-style mean aggregation: one wave per node ----------------
template<int D>
__global__ void aggregate_kernel(const float* __restrict__ feat, const int* __restrict__ offsets,
                                 const int* __restrict__ srcs, float* __restrict__ outmean) {
    int node = blockIdx.x * 4 + (threadIdx.x >> 6);
    if (node >= N_NODES) return;
    int lane = threadIdx.x & 63;
    int s = offsets[node], e = offsets[node + 1];
    float inv = 1.0f / (float)max(e - s, 1);
    if (D == 128) {
        float ax = 0.f, ay = 0.f;
        for (int j = s; j < e; ++j) {
            const float2 v = *(const float2*)(feat + (size_t)srcs[j] * 128 + lane * 2);
            ax += v.x; ay += v.y;
        }
        *(float2*)(outmean + (size_t)node * 128 + lane * 2) = make_float2(ax * inv, ay * inv);
    } else {
        float ax = 0.f, ay = 0.f, az = 0.f, aw = 0.f;
        for (int j = s; j < e; ++j) {
            const float4 v = *(const float4*)(feat + (size_t)srcs[j] * 256 + lane * 4);
            ax += v.x; ay += v.y; az += v.z; aw += v.w;
        }
        *(float4*)(outmean + (size_t)node * 256 + lane * 4) =
            make_float4(ax * inv, ay * inv, az * inv, aw * inv);
    }
}

// ---------------- fused dual-GEMM: out = [opt relu]( Am@Wl + As@Wr + bias ) ----------------
// BM=BN=64, BK=16, 256 threads (16x16), 4x4 micro-tile.
template<bool RELU>
__global__ __launch_bounds__(256)
void gemm_sage(const float* __restrict__ Am, const float* __restrict__ As,
               const float* __restrict__ Wl, const float* __restrict__ Wr,
               const float* __restrict__ bias, float* __restrict__ out,
               int N, int K, int NC) {
    __shared__ float sM[16][64];
    __shared__ float sS[16][64];
    __shared__ float sL[16][64];
    __shared__ float sR[16][64];
    const int tid = threadIdx.x;
    const int rowBase = blockIdx.x * 64;
    const int colBase = blockIdx.y * 64;
    const int ty = tid >> 4;           // 0..15
    const int tx = tid & 15;           // 0..15
    const int ar = tid >> 2;           // 0..63 : A-stage row
    const int ac = (tid & 3) * 4;      // 0,4,8,12 : A-stage k-offset
    const int wkr = tid >> 4;          // 0..15 : W-stage k-row
    const int wc  = (tid & 15) * 4;    // 0..60 : W-stage col

    float acc[4][4] = {{0.f}};

    for (int k0 = 0; k0 < K; k0 += 16) {
        // issue global loads for this tile
        float4 m4 = make_float4(0, 0, 0, 0), s4 = make_float4(0, 0, 0, 0);
        int grow = rowBase + ar;
        if (grow < N) {
            m4 = *(const float4*)(Am + (size_t)grow * K + k0 + ac);
            s4 = *(const float4*)(As + (size_t)grow * K + k0 + ac);
        }
        float4 l4 = *(const float4*)(Wl + (size_t)(k0 + wkr) * NC + colBase + wc);
        float4 r4 = *(const float4*)(Wr + (size_t)(k0 + wkr) * NC + colBase + wc);
        __syncthreads();   // previous compute done before overwriting tiles
        sM[ac + 0][ar] = m4.x; sM[ac + 1][ar] = m4.y; sM[ac + 2][ar] = m4.z; sM[ac + 3][ar] = m4.w;
        sS[ac + 0][ar] = s4.x; sS[ac + 1][ar] = s4.y; sS[ac + 2][ar] = s4.z; sS[ac + 3][ar] = s4.w;
        *(float4*)&sL[wkr][wc] = l4;
        *(float4*)&sR[wkr][wc] = r4;
        __syncthreads();
        #pragma unroll
        for (int k = 0; k < 16; ++k) {
            float4 a0 = *(const float4*)&sM[k][ty << 2];
            float4 a1 = *(const float4*)&sS[k][ty << 2];
            float4 b0 = *(const float4*)&sL[k][tx << 2];
            float4 b1 = *(const float4*)&sR[k][tx << 2];
            float A0[4] = {a0.x, a0.y, a0.z, a0.w};
            float A1[4] = {a1.x, a1.y, a1.z, a1.w};
            float B0[4] = {b0.x, b0.y, b0.z, b0.w};
            float B1[4] = {b1.x, b1.y, b1.z, b1.w};
            #pragma unroll
            for (int i = 0; i < 4; ++i)
                #pragma unroll
                for (int j = 0; j < 4; ++j)
                    acc[i][j] += A0[i] * B0[j] + A1[i] * B1[j];
        }
    }

    float4 bv = *(const float4*)(bias + colBase + (tx << 2));
    #pragma unroll
    for (int i = 0; i < 4; ++i) {
        int r = rowBase + (ty << 2) + i;
        if (r < N) {
            float4 o;
            o.x = acc[i][0] + bv.x;
            o.y = acc[i][1] + bv.y;
            o.z = acc[i][2] + bv.z;
            o.w = acc[i][3] + bv.w;
            if (RELU) {
                o.x = fmaxf(o.x, 0.f); o.y = fmaxf(o.y, 0.f);
                o.z = fmaxf(o.z, 0.f); o.w = fmaxf(o.w, 0.f);
            }
            *(float4*)(out + (size_t)r * NC + colBase + (tx << 2)) = o;
        }
    }
}

extern "C" void kernel_launch(void* const* d_in, const int* in_sizes, int n_in,
                              void* d_out, int out_size, void* d_ws, size_t ws_size,
                              hipStream_t stream) {
    const float* x   = (const float*)d_in[0];
    const int*   ei  = (const int*)d_in[1];
    const float* Wl1 = (const float*)d_in[2];
    const float* b1  = (const float*)d_in[3];
    const float* Wr1 = (const float*)d_in[4];
    const float* Wl2 = (const float*)d_in[5];
    const float* b2  = (const float*)d_in[6];
    const float* Wr2 = (const float*)d_in[7];
    const int E = in_sizes[1] / 2;
    const int* src = ei;
    const int* dst = ei + E;

    // workspace layout
    float* agg = (float*)d_ws;                                  // 100000*256 f32
    float* h   = agg + (size_t)N_NODES * 256;                   // 100000*256 f32
    int* counts  = (int*)(h + (size_t)N_NODES * 256);           // N
    int* offsets = counts + N_NODES;                            // N+1
    int* cursor  = offsets + N_NODES + 1;                       // N
    int* sorted  = cursor + N_NODES;                            // E

    hipMemsetAsync(counts, 0, N_NODES * sizeof(int), stream);
    hist_kernel<<<(E + 255) / 256, 256, 0, stream>>>(dst, counts, E);
    scan_kernel<<<1, 1024, 0, stream>>>(counts, offsets, cursor);
    fill_kernel<<<(E + 255) / 256, 256, 0, stream>>>(src, dst, cursor, sorted, E);

    // layer 1
    aggregate_kernel<128><<<(N_NODES + 3) / 4, 256, 0, stream>>>(x, offsets, sorted, agg);
    gemm_sage<true><<<dim3((N_NODES + 63) / 64, 4), 256, 0, stream>>>(
        agg, x, Wl1, Wr1, b1, h, N_NODES, 128, 256);

    // layer 2
    aggregate_kernel<256><<<(N_NODES + 3) / 4, 256, 0, stream>>>(h, offsets, sorted, agg);
    gemm_sage<false><<<dim3((N_NODES + 63) / 64, 2), 256, 0, stream>>>(
        agg, h, Wl2, Wr2, b2, (float*)d_out, N_NODES, 256, 128);
}

// Round 2
// 724.294 us; speedup vs baseline: 1.6076x; 1.6076x over previous
//
#include <hip/hip_runtime.h>

#define N_NODES 100000
#define NPAD 100096   // 391 * 256

using bf16x8 = __attribute__((ext_vector_type(8))) short;
using f32x4  = __attribute__((ext_vector_type(4))) float;

__device__ inline short f2bf(float f) {               // RNE f32 -> bf16
    unsigned int u = __float_as_uint(f);
    unsigned int r = (u + 0x7FFFu + ((u >> 16) & 1u)) >> 16;
    return (short)r;
}
__device__ inline float bf2f_lo(unsigned int w) { return __uint_as_float(w << 16); }
__device__ inline float bf2f_hi(unsigned int w) { return __uint_as_float(w & 0xFFFF0000u); }

// ---------------- histogram of dst ----------------
__global__ void hist_kernel(const int* __restrict__ dst, int* __restrict__ counts, int E) {
    int e = blockIdx.x * 256 + threadIdx.x;
    if (e < E) atomicAdd(&counts[dst[e]], 1);
}

// ---------------- single-block exclusive scan ----------------
__global__ void scan_kernel(const int* __restrict__ counts, int* __restrict__ offsets,
                            int* __restrict__ cursor) {
    const int tid  = threadIdx.x;          // 1024 threads
    const int lane = tid & 63;
    const int wave = tid >> 6;             // 16 waves
    __shared__ int wsum[16];
    __shared__ int carry;
    if (tid == 0) carry = 0;
    __syncthreads();
    for (int base = 0; base < N_NODES; base += 1024) {
        int i = base + tid;
        int v = (i < N_NODES) ? counts[i] : 0;
        int x = v;
        #pragma unroll
        for (int off = 1; off < 64; off <<= 1) {
            int t = __shfl_up(x, off, 64);
            if (lane >= off) x += t;
        }
        if (lane == 63) wsum[wave] = x;
        __syncthreads();
        int waveoff = 0, tot = 0;
        #pragma unroll
        for (int w = 0; w < 16; ++w) {
            int s = wsum[w];
            if (w < wave) waveoff += s;
            tot += s;
        }
        int excl = carry + waveoff + x - v;
        if (i < N_NODES) { offsets[i] = excl; cursor[i] = excl; }
        __syncthreads();
        if (tid == 0) carry += tot;
        __syncthreads();
    }
    if (tid == 0) offsets[N_NODES] = carry;
}

// ---------------- counting-sort placement ----------------
__global__ void fill_kernel(const int* __restrict__ src, const int* __restrict__ dst,
                            int* __restrict__ cursor, int* __restrict__ sorted_src, int E) {
    int e = blockIdx.x * 256 + threadIdx.x;
    if (e < E) {
        int p = atomicAdd(&cursor[dst[e]], 1);
        sorted_src[p] = src[e];
    }
}

// ---------------- cast x fp32 -> bf16 row-major + packed ----------------
__global__ void cast_x_kernel(const float* __restrict__ x, short* __restrict__ xrow,
                              short* __restrict__ xpack) {
    int t = blockIdx.x * 256 + threadIdx.x;
    if (t >= N_NODES * 16) return;
    int row = t >> 4;
    int kc = (t & 15) << 3;
    const float4 v0 = *(const float4*)(x + (size_t)row * 128 + kc);
    const float4 v1 = *(const float4*)(x + (size_t)row * 128 + kc + 4);
    __align__(16) short s[8] = {f2bf(v0.x), f2bf(v0.y), f2bf(v0.z), f2bf(v0.w),
                                f2bf(v1.x), f2bf(v1.y), f2bf(v1.z), f2bf(v1.w)};
    *(int4*)(xrow + (size_t)row * 128 + kc) = *(const int4*)s;
    size_t pidx = ((size_t)(row >> 4) * 16 + (kc >> 3)) * 128 + (size_t)(row & 15) * 8;
    *(int4*)(xpack + pidx) = *(const int4*)s;
}

// ---------------- pack weight fp32 [K][NC] -> bf16 fragment layout ----------------
__global__ void pack_w_kernel(const float* __restrict__ W, short* __restrict__ P,
                              int K, int NC) {
    int t = blockIdx.x * 256 + threadIdx.x;
    if (t >= K * NC) return;
    int k = t / NC, c = t % NC;
    P[((size_t)(c >> 4) * (K >> 3) + (k >> 3)) * 128 + (size_t)(c & 15) * 8 + (k & 7)] = f2bf(W[t]);
}

// ---------------- mean aggregation (bf16 in, packed bf16 out) ----------------
__global__ void aggregate1_kernel(const short* __restrict__ feat, const int* __restrict__ offsets,
                                  const int* __restrict__ srcs, short* __restrict__ outpack) {
    int node = blockIdx.x * 4 + (threadIdx.x >> 6);
    if (node >= N_NODES) return;
    int lane = threadIdx.x & 63;
    int s = offsets[node], e = offsets[node + 1];
    float inv = 1.0f / (float)max(e - s, 1);
    float a0 = 0.f, a1 = 0.f;
    for (int j = s; j < e; ++j) {
        unsigned int w = *(const unsigned int*)(feat + (size_t)srcs[j] * 128 + lane * 2);
        a0 += bf2f_lo(w); a1 += bf2f_hi(w);
    }
    __align__(4) short r[2] = {f2bf(a0 * inv), f2bf(a1 * inv)};
    int k = lane * 2;
    size_t pidx = ((size_t)(node >> 4) * 16 + (k >> 3)) * 128 + (size_t)(node & 15) * 8 + (k & 7);
    *(int*)(outpack + pidx) = *(const int*)r;
}

__global__ void aggregate2_kernel(const short* __restrict__ feat, const int* __restrict__ offsets,
                                  const int* __restrict__ srcs, short* __restrict__ outpack) {
    int node = blockIdx.x * 4 + (threadIdx.x >> 6);
    if (node >= N_NODES) return;
    int lane = threadIdx.x & 63;
    int s = offsets[node], e = offsets[node + 1];
    float inv = 1.0f / (float)max(e - s, 1);
    float a0 = 0.f, a1 = 0.f, a2 = 0.f, a3 = 0.f;
    for (int j = s; j < e; ++j) {
        uint2 w = *(const uint2*)(feat + (size_t)srcs[j] * 256 + lane * 4);
        a0 += bf2f_lo(w.x); a1 += bf2f_hi(w.x);
        a2 += bf2f_lo(w.y); a3 += bf2f_hi(w.y);
    }
    __align__(8) short r[4] = {f2bf(a0 * inv), f2bf(a1 * inv), f2bf(a2 * inv), f2bf(a3 * inv)};
    int k = lane * 4;
    size_t pidx = ((size_t)(node >> 4) * 32 + (k >> 3)) * 128 + (size_t)(node & 15) * 8 + (k & 7);
    *(int2*)(outpack + pidx) = *(const int2*)r;
}

// ---------------- MFMA dual-GEMM: out = [relu]( Am@Wl + As@Wr + bias ) ----------------
// 256 threads = 4 waves; wave computes 64 rows x 64 cols (4x4 fragments of 16x16x32).
template<int K, int NC, bool RELU, bool BF16OUT>
__global__ __launch_bounds__(256)
void gemm_mfma(const short* __restrict__ A0, const short* __restrict__ A1,
               const short* __restrict__ B0, const short* __restrict__ B1,
               const float* __restrict__ bias,
               short* __restrict__ orow, short* __restrict__ opack,
               float* __restrict__ of32) {
    constexpr int KB = K >> 3;           // 8-element k-chunks
    constexpr int S  = (K / 32) * 2;     // k-steps over both phases
    __shared__ float sC[4][32][68];

    const int tid  = threadIdx.x;
    const int wave = tid >> 6, lane = tid & 63;
    const int lhi  = lane >> 4, llo = lane & 15;
    const int rowBase = blockIdx.x * 256 + wave * 64;
    const int colBase = blockIdx.y * 64;
    const int rowTile = rowBase >> 4;
    const int colTile = colBase >> 4;

    f32x4 acc[4][4];
    #pragma unroll
    for (int i = 0; i < 4; ++i)
        #pragma unroll
        for (int j = 0; j < 4; ++j)
            #pragma unroll
            for (int r = 0; r < 4; ++r) acc[i][j][r] = 0.f;

    bf16x8 a[4], b[4];
    {   // preload step 0 (phase 0, k0 = 0)
        const int kb = lhi;
        #pragma unroll
        for (int i = 0; i < 4; ++i)
            a[i] = *(const bf16x8*)(A0 + ((size_t)(rowTile + i) * KB + kb) * 128 + (size_t)llo * 8);
        #pragma unroll
        for (int j = 0; j < 4; ++j)
            b[j] = *(const bf16x8*)(B0 + ((size_t)(colTile + j) * KB + kb) * 128 + (size_t)llo * 8);
    }

    #pragma unroll
    for (int s = 0; s < S; ++s) {
        bf16x8 an[4], bn[4];
        const bool has_next = (s + 1 < S);
        if (has_next) {
            const int s1 = s + 1;
            const int ph = (s1 >= S / 2) ? 1 : 0;
            const int k0 = (s1 - ph * (S / 2)) * 32;
            const int kb = (k0 >> 3) + lhi;
            const short* A = ph ? A1 : A0;
            const short* B = ph ? B1 : B0;
            #pragma unroll
            for (int i = 0; i < 4; ++i)
                an[i] = *(const bf16x8*)(A + ((size_t)(rowTile + i) * KB + kb) * 128 + (size_t)llo * 8);
            #pragma unroll
            for (int j = 0; j < 4; ++j)
                bn[j] = *(const bf16x8*)(B + ((size_t)(colTile + j) * KB + kb) * 128 + (size_t)llo * 8);
        }
        #pragma unroll
        for (int i = 0; i < 4; ++i)
            #pragma unroll
            for (int j = 0; j < 4; ++j)
                acc[i][j] = __builtin_amdgcn_mfma_f32_16x16x32_bf16(a[i], b[j], acc[i][j], 0, 0, 0);
        if (has_next) {
            #pragma unroll
            for (int i = 0; i < 4; ++i) a[i] = an[i];
            #pragma unroll
            for (int j = 0; j < 4; ++j) b[j] = bn[j];
        }
    }

    // bias + relu
    #pragma unroll
    for (int j = 0; j < 4; ++j) {
        float bv = bias[colBase + j * 16 + llo];
        #pragma unroll
        for (int i = 0; i < 4; ++i)
            #pragma unroll
            for (int r = 0; r < 4; ++r) {
                float v = acc[i][j][r] + bv;
                acc[i][j][r] = RELU ? fmaxf(v, 0.f) : v;
            }
    }

    // LDS transpose epilogue, 32 rows at a time (per-wave buffer, no block barrier)
    #pragma unroll
    for (int half = 0; half < 2; ++half) {
        #pragma unroll
        for (int i2 = 0; i2 < 2; ++i2) {
            const int i = half * 2 + i2;
            #pragma unroll
            for (int j = 0; j < 4; ++j)
                #pragma unroll
                for (int r = 0; r < 4; ++r)
                    sC[wave][i2 * 16 + lhi * 4 + r][j * 16 + llo] = acc[i][j][r];
        }
        #pragma unroll
        for (int it = 0; it < 4; ++it) {
            const int r = it * 8 + (lane >> 3);
            const int c = (lane & 7) * 8;
            const int grow = rowBase + half * 32 + r;
            if (grow < N_NODES) {
                float4 v0 = *(const float4*)&sC[wave][r][c];
                float4 v1 = *(const float4*)&sC[wave][r][c + 4];
                if (BF16OUT) {
                    __align__(16) short sv[8] = {f2bf(v0.x), f2bf(v0.y), f2bf(v0.z), f2bf(v0.w),
                                                 f2bf(v1.x), f2bf(v1.y), f2bf(v1.z), f2bf(v1.w)};
                    *(int4*)(orow + (size_t)grow * NC + colBase + c) = *(const int4*)sv;
                    size_t pidx = ((size_t)(grow >> 4) * (NC >> 3) + ((colBase + c) >> 3)) * 128
                                + (size_t)(grow & 15) * 8;
                    *(int4*)(opack + pidx) = *(const int4*)sv;
                } else {
                    *(float4*)(of32 + (size_t)grow * NC + colBase + c) = v0;
                    *(float4*)(of32 + (size_t)grow * NC + colBase + c + 4) = v1;
                }
            }
        }
    }
}

extern "C" void kernel_launch(void* const* d_in, const int* in_sizes, int n_in,
                              void* d_out, int out_size, void* d_ws, size_t ws_size,
                              hipStream_t stream) {
    const float* x   = (const float*)d_in[0];
    const int*   ei  = (const int*)d_in[1];
    const float* Wl1 = (const float*)d_in[2];
    const float* b1  = (const float*)d_in[3];
    const float* Wr1 = (const float*)d_in[4];
    const float* Wl2 = (const float*)d_in[5];
    const float* b2  = (const float*)d_in[6];
    const float* Wr2 = (const float*)d_in[7];
    const int E = in_sizes[1] / 2;
    const int* src = ei;
    const int* dst = ei + E;

    // workspace layout (shorts)
    short* h_row  = (short*)d_ws;                 // NPAD*256
    short* h_pack = h_row  + (size_t)NPAD * 256;  // NPAD*256
    short* agg1p  = h_pack + (size_t)NPAD * 256;  // NPAD*128
    short* xreg   = agg1p  + (size_t)NPAD * 128;  // NPAD*256 (x_row + x_pack; later agg2p)
    short* x_row  = xreg;
    short* x_pack = xreg   + (size_t)NPAD * 128;
    short* agg2p  = xreg;                         // reuse after gemm1
    short* wl1p   = xreg   + (size_t)NPAD * 256;
    short* wr1p   = wl1p + 32768;
    short* wl2p   = wr1p + 32768;
    short* wr2p   = wl2p + 32768;
    int* counts  = (int*)(wr2p + 32768);
    int* offsets = counts + N_NODES;
    int* cursor  = offsets + N_NODES + 1;
    int* sorted  = cursor + N_NODES;

    // CSR build
    hipMemsetAsync(counts, 0, N_NODES * sizeof(int), stream);
    hist_kernel<<<(E + 255) / 256, 256, 0, stream>>>(dst, counts, E);
    scan_kernel<<<1, 1024, 0, stream>>>(counts, offsets, cursor);
    fill_kernel<<<(E + 255) / 256, 256, 0, stream>>>(src, dst, cursor, sorted, E);

    // bf16 conversions / packing
    cast_x_kernel<<<(N_NODES * 16 + 255) / 256, 256, 0, stream>>>(x, x_row, x_pack);
    pack_w_kernel<<<128, 256, 0, stream>>>(Wl1, wl1p, 128, 256);
    pack_w_kernel<<<128, 256, 0, stream>>>(Wr1, wr1p, 128, 256);
    pack_w_kernel<<<128, 256, 0, stream>>>(Wl2, wl2p, 256, 128);
    pack_w_kernel<<<128, 256, 0, stream>>>(Wr2, wr2p, 256, 128);

    // layer 1
    aggregate1_kernel<<<N_NODES / 4, 256, 0, stream>>>(x_row, offsets, sorted, agg1p);
    gemm_mfma<128, 256, true, true><<<dim3(NPAD / 256, 4), 256, 0, stream>>>(
        agg1p, x_pack, wl1p, wr1p, b1, h_row, h_pack, nullptr);

    // layer 2
    aggregate2_kernel<<<N_NODES / 4, 256, 0, stream>>>(h_row, offsets, sorted, agg2p);
    gemm_mfma<256, 128, false, false><<<dim3(NPAD / 256, 2), 256, 0, stream>>>(
        agg2p, h_pack, wl2p, wr2p, b2, nullptr, nullptr, (float*)d_out);
}

// Round 3
// 463.320 us; speedup vs baseline: 2.5131x; 1.5633x over previous
//
#include <hip/hip_runtime.h>

#define N_NODES 100000
#define NPAD 100096   // 391 * 256
#define NBLK 391

using bf16x8 = __attribute__((ext_vector_type(8))) short;
using f32x4  = __attribute__((ext_vector_type(4))) float;

__device__ inline short f2bf(float f) {               // RNE f32 -> bf16
    unsigned int u = __float_as_uint(f);
    unsigned int r = (u + 0x7FFFu + ((u >> 16) & 1u)) >> 16;
    return (short)r;
}
__device__ inline float bf2f_lo(unsigned int w) { return __uint_as_float(w << 16); }
__device__ inline float bf2f_hi(unsigned int w) { return __uint_as_float(w & 0xFFFF0000u); }

// ---------------- histogram of dst ----------------
__global__ void hist_kernel(const int* __restrict__ dst, int* __restrict__ counts, int E) {
    int e = blockIdx.x * 256 + threadIdx.x;
    if (e < E) atomicAdd(&counts[dst[e]], 1);
}

// ---------------- multi-block scan: bsum -> bscan -> escan ----------------
__global__ void bsum_kernel(const int* __restrict__ counts, int* __restrict__ bsum) {
    int i = blockIdx.x * 256 + threadIdx.x;
    int v = (i < N_NODES) ? counts[i] : 0;
    #pragma unroll
    for (int off = 32; off; off >>= 1) v += __shfl_xor(v, off, 64);
    __shared__ int ws[4];
    int lane = threadIdx.x & 63, wave = threadIdx.x >> 6;
    if (lane == 0) ws[wave] = v;
    __syncthreads();
    if (threadIdx.x == 0) bsum[blockIdx.x] = ws[0] + ws[1] + ws[2] + ws[3];
}

__global__ void bscan_kernel(const int* __restrict__ bsum, int* __restrict__ boff,
                             int* __restrict__ offsets) {
    __shared__ int s[512];
    int t = threadIdx.x;
    int v = (t < NBLK) ? bsum[t] : 0;
    s[t] = v;
    __syncthreads();
    #pragma unroll
    for (int off = 1; off < 512; off <<= 1) {
        int u = (t >= off) ? s[t - off] : 0;
        __syncthreads();
        s[t] += u;
        __syncthreads();
    }
    if (t < NBLK) boff[t] = s[t] - v;           // exclusive
    if (t == NBLK - 1) offsets[N_NODES] = s[t]; // total = E
}

__global__ void escan_kernel(const int* __restrict__ counts, const int* __restrict__ boff,
                             int* __restrict__ offsets, int* __restrict__ cursor) {
    const int tid = threadIdx.x;
    const int lane = tid & 63, wave = tid >> 6;
    const int i = blockIdx.x * 256 + tid;
    int v = (i < N_NODES) ? counts[i] : 0;
    int x = v;
    #pragma unroll
    for (int off = 1; off < 64; off <<= 1) {
        int t = __shfl_up(x, off, 64);
        if (lane >= off) x += t;
    }
    __shared__ int wsum[4];
    if (lane == 63) wsum[wave] = x;
    __syncthreads();
    int woff = 0;
    #pragma unroll
    for (int w = 0; w < 4; ++w) if (w < wave) woff += wsum[w];
    int excl = boff[blockIdx.x] + woff + x - v;
    if (i < N_NODES) { offsets[i] = excl; cursor[i] = excl; }
}

// ---------------- counting-sort placement ----------------
__global__ void fill_kernel(const int* __restrict__ src, const int* __restrict__ dst,
                            int* __restrict__ cursor, int* __restrict__ sorted_src, int E) {
    int e = blockIdx.x * 256 + threadIdx.x;
    if (e < E) {
        int p = atomicAdd(&cursor[dst[e]], 1);
        sorted_src[p] = src[e];
    }
}

// ---------------- cast x fp32 -> bf16 row-major + packed ----------------
__global__ void cast_x_kernel(const float* __restrict__ x, short* __restrict__ xrow,
                              short* __restrict__ xpack) {
    int t = blockIdx.x * 256 + threadIdx.x;
    if (t >= N_NODES * 16) return;
    int row = t >> 4;
    int kc = (t & 15) << 3;
    const float4 v0 = *(const float4*)(x + (size_t)row * 128 + kc);
    const float4 v1 = *(const float4*)(x + (size_t)row * 128 + kc + 4);
    __align__(16) short s[8] = {f2bf(v0.x), f2bf(v0.y), f2bf(v0.z), f2bf(v0.w),
                                f2bf(v1.x), f2bf(v1.y), f2bf(v1.z), f2bf(v1.w)};
    *(int4*)(xrow + (size_t)row * 128 + kc) = *(const int4*)s;
    size_t pidx = ((size_t)(row >> 4) * 16 + (kc >> 3)) * 128 + (size_t)(row & 15) * 8;
    *(int4*)(xpack + pidx) = *(const int4*)s;
}

// ---------------- pack weight fp32 [K][NC] -> bf16 fragment layout ----------------
__global__ void pack_w_kernel(const float* __restrict__ W, short* __restrict__ P,
                              int K, int NC) {
    int t = blockIdx.x * 256 + threadIdx.x;
    if (t >= K * NC) return;
    int k = t / NC, c = t % NC;
    P[((size_t)(c >> 4) * (K >> 3) + (k >> 3)) * 128 + (size_t)(c & 15) * 8 + (k & 7)] = f2bf(W[t]);
}

// ---------------- mean aggregation over 128-dim bf16 rows ----------------
// wave = 4 groups of 16 lanes; group g gathers row srcs[j], j = s+g, s+g+4, ...
// MODE 0: write packed bf16 (GEMM A-operand). MODE 1: d_out[node] += mean (f32 RMW).
template<int MODE>
__global__ __launch_bounds__(256)
void aggregate128_kernel(const short* __restrict__ feat, const int* __restrict__ offsets,
                         const int* __restrict__ srcs,
                         short* __restrict__ outpack, float* __restrict__ outf) {
    int node = blockIdx.x * 4 + (threadIdx.x >> 6);
    if (node >= N_NODES) return;
    const int lane = threadIdx.x & 63;
    const int g = lane >> 4, p = lane & 15;
    const int s = offsets[node], e = offsets[node + 1];
    const float inv = 1.0f / (float)max(e - s, 1);
    float acc[8] = {0.f, 0.f, 0.f, 0.f, 0.f, 0.f, 0.f, 0.f};
    for (int j = s + g; j < e; j += 4) {
        const uint4 w = *(const uint4*)(feat + (size_t)srcs[j] * 128 + p * 8);
        acc[0] += bf2f_lo(w.x); acc[1] += bf2f_hi(w.x);
        acc[2] += bf2f_lo(w.y); acc[3] += bf2f_hi(w.y);
        acc[4] += bf2f_lo(w.z); acc[5] += bf2f_hi(w.z);
        acc[6] += bf2f_lo(w.w); acc[7] += bf2f_hi(w.w);
    }
    #pragma unroll
    for (int t = 0; t < 8; ++t) acc[t] += __shfl_xor(acc[t], 16, 64);
    #pragma unroll
    for (int t = 0; t < 8; ++t) acc[t] += __shfl_xor(acc[t], 32, 64);
    if (g != 0) return;
    if (MODE == 0) {
        __align__(16) short r[8];
        #pragma unroll
        for (int t = 0; t < 8; ++t) r[t] = f2bf(acc[t] * inv);
        size_t pidx = ((size_t)(node >> 4) * 16 + p) * 128 + (size_t)(node & 15) * 8;
        *(int4*)(outpack + pidx) = *(const int4*)r;
    } else {
        float* o = outf + (size_t)node * 128 + p * 8;
        float4 q0 = *(const float4*)o;
        float4 q1 = *(const float4*)(o + 4);
        q0.x += acc[0] * inv; q0.y += acc[1] * inv; q0.z += acc[2] * inv; q0.w += acc[3] * inv;
        q1.x += acc[4] * inv; q1.y += acc[5] * inv; q1.z += acc[6] * inv; q1.w += acc[7] * inv;
        *(float4*)o = q0;
        *(float4*)(o + 4) = q1;
    }
}

// ---------------- MFMA GEMM ----------------
// DUAL: acc = A0@B0 + A1@B1 (phase-split over S). Single: acc = A0@B0.
// OMODE 0: packed bf16 out. OMODE 1: row-major bf16 out. OMODE 2: f32 out (+bias).
// Bias applied when OMODE != 1.
template<int K, int NC, bool DUAL, bool RELU, int OMODE>
__global__ __launch_bounds__(256)
void gemm_mfma(const short* __restrict__ A0, const short* __restrict__ A1,
               const short* __restrict__ B0, const short* __restrict__ B1,
               const float* __restrict__ bias,
               short* __restrict__ obf, float* __restrict__ of32) {
    constexpr int KB = K >> 3;           // 8-element k-chunks per row
    constexpr int KS = K / 32;           // k-steps per phase
    constexpr int S  = (DUAL ? 2 : 1) * KS;
    __shared__ float sC[4][32][68];

    const int tid  = threadIdx.x;
    const int wave = tid >> 6, lane = tid & 63;
    const int lhi  = lane >> 4, llo = lane & 15;
    const int rowBase = blockIdx.x * 256 + wave * 64;
    const int colBase = blockIdx.y * 64;
    const int rowTile = rowBase >> 4;
    const int colTile = colBase >> 4;

    f32x4 acc[4][4];
    #pragma unroll
    for (int i = 0; i < 4; ++i)
        #pragma unroll
        for (int j = 0; j < 4; ++j)
            #pragma unroll
            for (int r = 0; r < 4; ++r) acc[i][j][r] = 0.f;

    bf16x8 a[4], b[4];
    {   // preload step 0
        const int kb = lhi;
        #pragma unroll
        for (int i = 0; i < 4; ++i)
            a[i] = *(const bf16x8*)(A0 + ((size_t)(rowTile + i) * KB + kb) * 128 + (size_t)llo * 8);
        #pragma unroll
        for (int j = 0; j < 4; ++j)
            b[j] = *(const bf16x8*)(B0 + ((size_t)(colTile + j) * KB + kb) * 128 + (size_t)llo * 8);
    }

    #pragma unroll
    for (int s = 0; s < S; ++s) {
        bf16x8 an[4], bn[4];
        const bool has_next = (s + 1 < S);
        if (has_next) {
            const int s1 = s + 1;
            const int ph = (DUAL && s1 >= KS) ? 1 : 0;
            const int k0 = (s1 - ph * KS) * 32;
            const int kb = (k0 >> 3) + lhi;
            const short* A = ph ? A1 : A0;
            const short* B = ph ? B1 : B0;
            #pragma unroll
            for (int i = 0; i < 4; ++i)
                an[i] = *(const bf16x8*)(A + ((size_t)(rowTile + i) * KB + kb) * 128 + (size_t)llo * 8);
            #pragma unroll
            for (int j = 0; j < 4; ++j)
                bn[j] = *(const bf16x8*)(B + ((size_t)(colTile + j) * KB + kb) * 128 + (size_t)llo * 8);
        }
        #pragma unroll
        for (int i = 0; i < 4; ++i)
            #pragma unroll
            for (int j = 0; j < 4; ++j)
                acc[i][j] = __builtin_amdgcn_mfma_f32_16x16x32_bf16(a[i], b[j], acc[i][j], 0, 0, 0);
        if (has_next) {
            #pragma unroll
            for (int i = 0; i < 4; ++i) a[i] = an[i];
            #pragma unroll
            for (int j = 0; j < 4; ++j) b[j] = bn[j];
        }
    }

    // bias + relu
    #pragma unroll
    for (int j = 0; j < 4; ++j) {
        float bv = (OMODE != 1) ? bias[colBase + j * 16 + llo] : 0.f;
        #pragma unroll
        for (int i = 0; i < 4; ++i)
            #pragma unroll
            for (int r = 0; r < 4; ++r) {
                float v = acc[i][j][r] + bv;
                acc[i][j][r] = RELU ? fmaxf(v, 0.f) : v;
            }
    }

    // LDS transpose epilogue, 32 rows at a time (per-wave buffer, no block barrier)
    #pragma unroll
    for (int half = 0; half < 2; ++half) {
        #pragma unroll
        for (int i2 = 0; i2 < 2; ++i2) {
            const int i = half * 2 + i2;
            #pragma unroll
            for (int j = 0; j < 4; ++j)
                #pragma unroll
                for (int r = 0; r < 4; ++r)
                    sC[wave][i2 * 16 + lhi * 4 + r][j * 16 + llo] = acc[i][j][r];
        }
        #pragma unroll
        for (int it = 0; it < 4; ++it) {
            const int r = it * 8 + (lane >> 3);
            const int c = (lane & 7) * 8;
            const int grow = rowBase + half * 32 + r;
            if (grow < N_NODES) {
                float4 v0 = *(const float4*)&sC[wave][r][c];
                float4 v1 = *(const float4*)&sC[wave][r][c + 4];
                if (OMODE == 2) {
                    *(float4*)(of32 + (size_t)grow * NC + colBase + c) = v0;
                    *(float4*)(of32 + (size_t)grow * NC + colBase + c + 4) = v1;
                } else {
                    __align__(16) short sv[8] = {f2bf(v0.x), f2bf(v0.y), f2bf(v0.z), f2bf(v0.w),
                                                 f2bf(v1.x), f2bf(v1.y), f2bf(v1.z), f2bf(v1.w)};
                    if (OMODE == 1) {
                        *(int4*)(obf + (size_t)grow * NC + colBase + c) = *(const int4*)sv;
                    } else {
                        size_t pidx = ((size_t)(grow >> 4) * (NC >> 3) + ((colBase + c) >> 3)) * 128
                                    + (size_t)(grow & 15) * 8;
                        *(int4*)(obf + pidx) = *(const int4*)sv;
                    }
                }
            }
        }
    }
}

extern "C" void kernel_launch(void* const* d_in, const int* in_sizes, int n_in,
                              void* d_out, int out_size, void* d_ws, size_t ws_size,
                              hipStream_t stream) {
    const float* x   = (const float*)d_in[0];
    const int*   ei  = (const int*)d_in[1];
    const float* Wl1 = (const float*)d_in[2];
    const float* b1  = (const float*)d_in[3];
    const float* Wr1 = (const float*)d_in[4];
    const float* Wl2 = (const float*)d_in[5];
    const float* b2  = (const float*)d_in[6];
    const float* Wr2 = (const float*)d_in[7];
    const int E = in_sizes[1] / 2;
    const int* src = ei;
    const int* dst = ei + E;

    // workspace layout
    short* h_pack = (short*)d_ws;                   // NPAD*256
    short* agg1p  = h_pack + (size_t)NPAD * 256;    // NPAD*128
    short* x_row  = agg1p  + (size_t)NPAD * 128;    // NPAD*128
    short* x_pack = x_row  + (size_t)NPAD * 128;    // NPAD*128
    short* p_row  = x_pack + (size_t)NPAD * 128;    // NPAD*128
    short* wl1p   = p_row  + (size_t)NPAD * 128;    // 32768
    short* wr1p   = wl1p + 32768;
    short* wl2p   = wr1p + 32768;
    short* wr2p   = wl2p + 32768;
    int* counts  = (int*)(wr2p + 32768);            // N
    int* offsets = counts + N_NODES;                // N+1
    int* cursor  = offsets + N_NODES + 1;           // N
    int* bsum    = cursor + N_NODES;                // NBLK
    int* boff    = bsum + NBLK;                     // NBLK
    int* sorted  = boff + NBLK;                     // E

    // CSR build
    hipMemsetAsync(counts, 0, N_NODES * sizeof(int), stream);
    hist_kernel<<<(E + 255) / 256, 256, 0, stream>>>(dst, counts, E);
    bsum_kernel<<<NBLK, 256, 0, stream>>>(counts, bsum);
    bscan_kernel<<<1, 512, 0, stream>>>(bsum, boff, offsets);
    escan_kernel<<<NBLK, 256, 0, stream>>>(counts, boff, offsets, cursor);
    fill_kernel<<<(E + 255) / 256, 256, 0, stream>>>(src, dst, cursor, sorted, E);

    // bf16 conversions / packing
    cast_x_kernel<<<(N_NODES * 16 + 255) / 256, 256, 0, stream>>>(x, x_row, x_pack);
    pack_w_kernel<<<128, 256, 0, stream>>>(Wl1, wl1p, 128, 256);
    pack_w_kernel<<<128, 256, 0, stream>>>(Wr1, wr1p, 128, 256);
    pack_w_kernel<<<128, 256, 0, stream>>>(Wl2, wl2p, 256, 128);
    pack_w_kernel<<<128, 256, 0, stream>>>(Wr2, wr2p, 256, 128);

    // layer 1: agg(x) -> h = relu([mean,x]@[Wl1;Wr1] + b1) (packed only)
    aggregate128_kernel<0><<<N_NODES / 4, 256, 0, stream>>>(x_row, offsets, sorted, agg1p, nullptr);
    gemm_mfma<128, 256, true, true, 0><<<dim3(NPAD / 256, 4), 256, 0, stream>>>(
        agg1p, x_pack, wl1p, wr1p, b1, h_pack, nullptr);

    // layer 2 (commuted): p = h@Wl2 (bf16 rows); d_out = h@Wr2 + b2; d_out += mean(p)
    gemm_mfma<256, 128, false, false, 1><<<dim3(NPAD / 256, 2), 256, 0, stream>>>(
        h_pack, nullptr, wl2p, nullptr, nullptr, p_row, nullptr);
    gemm_mfma<256, 128, false, false, 2><<<dim3(NPAD / 256, 2), 256, 0, stream>>>(
        h_pack, nullptr, wr2p, nullptr, b2, nullptr, (float*)d_out);
    aggregate128_kernel<1><<<N_NODES / 4, 256, 0, stream>>>(p_row, offsets, sorted, nullptr, (float*)d_out);
}

// Round 4
// 304.318 us; speedup vs baseline: 3.8261x; 1.5225x over previous
//
#include <hip/hip_runtime.h>

#define N_NODES 100000
#define NPAD 100096   // 391 * 256
#define NBLK 391      // dst buckets of 256 nodes

using bf16x8 = __attribute__((ext_vector_type(8))) short;
using f32x4  = __attribute__((ext_vector_type(4))) float;

__device__ inline short f2bf(float f) {               // RNE f32 -> bf16
    unsigned int u = __float_as_uint(f);
    unsigned int r = (u + 0x7FFFu + ((u >> 16) & 1u)) >> 16;
    return (short)r;
}
__device__ inline float bf2f_lo(unsigned int w) { return __uint_as_float(w << 16); }
__device__ inline float bf2f_hi(unsigned int w) { return __uint_as_float(w & 0xFFFF0000u); }

// ---------------- pass 0: bucket histogram (LDS pre-reduce) ----------------
__global__ __launch_bounds__(256)
void cbuck_kernel(const int* __restrict__ dst, int* __restrict__ bucket_cnt, int E) {
    __shared__ int cnt[NBLK];
    const int tid = threadIdx.x;
    for (int i = tid; i < NBLK; i += 256) cnt[i] = 0;
    __syncthreads();
    const int e0 = blockIdx.x * 4096;
    #pragma unroll
    for (int k = 0; k < 16; ++k) {
        int e = e0 + k * 256 + tid;
        if (e < E) atomicAdd(&cnt[dst[e] >> 8], 1);
    }
    __syncthreads();
    for (int i = tid; i < NBLK; i += 256)
        if (cnt[i]) atomicAdd(&bucket_cnt[i], cnt[i]);
}

// ---------------- pass 1: scan of 391 bucket counts ----------------
__global__ void scan391_kernel(const int* __restrict__ bucket_cnt, int* __restrict__ bucket_base,
                               int* __restrict__ bucket_cursor, int* __restrict__ offsets) {
    __shared__ int s[512];
    int t = threadIdx.x;
    int v = (t < NBLK) ? bucket_cnt[t] : 0;
    s[t] = v;
    __syncthreads();
    #pragma unroll
    for (int off = 1; off < 512; off <<= 1) {
        int u = (t >= off) ? s[t - off] : 0;
        __syncthreads();
        s[t] += u;
        __syncthreads();
    }
    if (t < NBLK) {
        int excl = s[t] - v;
        bucket_base[t] = excl;
        bucket_cursor[t] = excl;
    }
    if (t == NBLK - 1) {
        bucket_base[NBLK] = s[t];
        offsets[N_NODES] = s[t];      // = E
    }
}

// ---------------- pass 2: bin edges by dst>>8, dense packed writes ----------------
__global__ __launch_bounds__(256)
void bin_kernel(const int* __restrict__ src, const int* __restrict__ dst,
                int* __restrict__ bucket_cursor, unsigned int* __restrict__ bin, int E) {
    __shared__ int cnt[NBLK];
    __shared__ int base_l[NBLK];
    const int tid = threadIdx.x;
    const int e0 = blockIdx.x * 4096;
    for (int i = tid; i < NBLK; i += 256) cnt[i] = 0;
    __syncthreads();
    int myb[16]; unsigned myv[16];
    #pragma unroll
    for (int k = 0; k < 16; ++k) {
        int e = e0 + k * 256 + tid;
        if (e < E) {
            int d = dst[e];
            myb[k] = d >> 8;
            myv[k] = (unsigned)src[e] | ((unsigned)(d & 255) << 20);
            atomicAdd(&cnt[myb[k]], 1);
        } else myb[k] = -1;
    }
    __syncthreads();
    for (int i = tid; i < NBLK; i += 256) {
        int c = cnt[i];
        base_l[i] = c ? atomicAdd(&bucket_cursor[i], c) : 0;
        cnt[i] = 0;
    }
    __syncthreads();
    #pragma unroll
    for (int k = 0; k < 16; ++k) {
        if (myb[k] >= 0) {
            int slot = base_l[myb[k]] + atomicAdd(&cnt[myb[k]], 1);
            bin[slot] = myv[k];
        }
    }
}

// ---------------- pass 3: per-bucket place; also emits per-node offsets ----------------
__global__ __launch_bounds__(256)
void place_kernel(const unsigned int* __restrict__ bin, const int* __restrict__ bucket_base,
                  int* __restrict__ offsets, int* __restrict__ sorted) {
    __shared__ int cnt[256];
    __shared__ int cur[256];
    __shared__ int wsum[4];
    const int b = blockIdx.x, tid = threadIdx.x;
    const int lane = tid & 63, wave = tid >> 6;
    const int s = bucket_base[b];
    const int e = bucket_base[b + 1];
    cnt[tid] = 0;
    __syncthreads();
    for (int i = s + tid; i < e; i += 256) atomicAdd(&cnt[bin[i] >> 20], 1);
    __syncthreads();
    int v = cnt[tid];
    int x = v;
    #pragma unroll
    for (int off = 1; off < 64; off <<= 1) {
        int t = __shfl_up(x, off, 64);
        if (lane >= off) x += t;
    }
    if (lane == 63) wsum[wave] = x;
    __syncthreads();
    int woff = 0;
    #pragma unroll
    for (int w = 0; w < 4; ++w) if (w < wave) woff += wsum[w];
    int excl = s + woff + x - v;
    cur[tid] = excl;
    int node = b * 256 + tid;
    if (node < N_NODES) offsets[node] = excl;
    __syncthreads();
    for (int i = s + tid; i < e; i += 256) {
        unsigned w = bin[i];
        int p = atomicAdd(&cur[w >> 20], 1);
        sorted[p] = (int)(w & 0xFFFFFu);
    }
}

// ---------------- cast x fp32 -> bf16 row-major + packed ----------------
__global__ void cast_x_kernel(const float* __restrict__ x, short* __restrict__ xrow,
                              short* __restrict__ xpack) {
    int t = blockIdx.x * 256 + threadIdx.x;
    if (t >= N_NODES * 16) return;
    int row = t >> 4;
    int kc = (t & 15) << 3;
    const float4 v0 = *(const float4*)(x + (size_t)row * 128 + kc);
    const float4 v1 = *(const float4*)(x + (size_t)row * 128 + kc + 4);
    __align__(16) short s[8] = {f2bf(v0.x), f2bf(v0.y), f2bf(v0.z), f2bf(v0.w),
                                f2bf(v1.x), f2bf(v1.y), f2bf(v1.z), f2bf(v1.w)};
    *(int4*)(xrow + (size_t)row * 128 + kc) = *(const int4*)s;
    size_t pidx = ((size_t)(row >> 4) * 16 + (kc >> 3)) * 128 + (size_t)(row & 15) * 8;
    *(int4*)(xpack + pidx) = *(const int4*)s;
}

// ---------------- pack weight fp32 [K][NC] -> bf16 fragment layout ----------------
__global__ void pack_w_kernel(const float* __restrict__ W, short* __restrict__ P,
                              int K, int NC) {
    int t = blockIdx.x * 256 + threadIdx.x;
    if (t >= K * NC) return;
    int k = t / NC, c = t % NC;
    P[((size_t)(c >> 4) * (K >> 3) + (k >> 3)) * 128 + (size_t)(c & 15) * 8 + (k & 7)] = f2bf(W[t]);
}

// ---------------- mean aggregation over 128-dim bf16 rows, 2x unrolled ----------------
// wave = 4 groups of 16 lanes; group g gathers rows srcs[s+g+4t].
// MODE 0: write packed bf16 (GEMM A-operand). MODE 1: outf[node] += mean (f32 RMW).
template<int MODE>
__global__ __launch_bounds__(256)
void aggregate128_kernel(const short* __restrict__ feat, const int* __restrict__ offsets,
                         const int* __restrict__ srcs,
                         short* __restrict__ outpack, float* __restrict__ outf) {
    int node = blockIdx.x * 4 + (threadIdx.x >> 6);
    if (node >= N_NODES) return;
    const int lane = threadIdx.x & 63;
    const int g = lane >> 4, p = lane & 15;
    const int s = offsets[node], e = offsets[node + 1];
    const float inv = 1.0f / (float)max(e - s, 1);
    float acc[8] = {0.f, 0.f, 0.f, 0.f, 0.f, 0.f, 0.f, 0.f};
    for (int j = s + g; j < e; j += 8) {
        const int j2 = j + 4;
        const bool h2 = (j2 < e);
        const int i0 = srcs[j];
        const int i1 = h2 ? srcs[j2] : i0;
        const uint4 w0 = *(const uint4*)(feat + (size_t)i0 * 128 + p * 8);
        const uint4 w1 = *(const uint4*)(feat + (size_t)i1 * 128 + p * 8);
        acc[0] += bf2f_lo(w0.x); acc[1] += bf2f_hi(w0.x);
        acc[2] += bf2f_lo(w0.y); acc[3] += bf2f_hi(w0.y);
        acc[4] += bf2f_lo(w0.z); acc[5] += bf2f_hi(w0.z);
        acc[6] += bf2f_lo(w0.w); acc[7] += bf2f_hi(w0.w);
        if (h2) {
            acc[0] += bf2f_lo(w1.x); acc[1] += bf2f_hi(w1.x);
            acc[2] += bf2f_lo(w1.y); acc[3] += bf2f_hi(w1.y);
            acc[4] += bf2f_lo(w1.z); acc[5] += bf2f_hi(w1.z);
            acc[6] += bf2f_lo(w1.w); acc[7] += bf2f_hi(w1.w);
        }
    }
    #pragma unroll
    for (int t = 0; t < 8; ++t) acc[t] += __shfl_xor(acc[t], 16, 64);
    #pragma unroll
    for (int t = 0; t < 8; ++t) acc[t] += __shfl_xor(acc[t], 32, 64);
    if (g != 0) return;
    if (MODE == 0) {
        __align__(16) short r[8];
        #pragma unroll
        for (int t = 0; t < 8; ++t) r[t] = f2bf(acc[t] * inv);
        size_t pidx = ((size_t)(node >> 4) * 16 + p) * 128 + (size_t)(node & 15) * 8;
        *(int4*)(outpack + pidx) = *(const int4*)r;
    } else {
        float* o = outf + (size_t)node * 128 + p * 8;
        float4 q0 = *(const float4*)o;
        float4 q1 = *(const float4*)(o + 4);
        q0.x += acc[0] * inv; q0.y += acc[1] * inv; q0.z += acc[2] * inv; q0.w += acc[3] * inv;
        q1.x += acc[4] * inv; q1.y += acc[5] * inv; q1.z += acc[6] * inv; q1.w += acc[7] * inv;
        *(float4*)o = q0;
        *(float4*)(o + 4) = q1;
    }
}

// ---------------- layer-1 GEMM: h = relu(A0@B0 + A1@B1 + bias), packed bf16 out ----------------
// wave tile 64 rows x 128 cols; grid (NPAD/256, 2). K per phase = 128.
__global__ __launch_bounds__(256)
void gemm1_kernel(const short* __restrict__ A0, const short* __restrict__ A1,
                  const short* __restrict__ B0, const short* __restrict__ B1,
                  const float* __restrict__ bias, short* __restrict__ opack) {
    constexpr int KB = 16, KS = 4, S = 8;   // k-chunks/row, steps/phase, total steps
    __shared__ float sC[4][32][132];
    const int tid = threadIdx.x, wave = tid >> 6, lane = tid & 63;
    const int lhi = lane >> 4, llo = lane & 15;
    const int rowBase = blockIdx.x * 256 + wave * 64;
    const int colBase = blockIdx.y * 128;
    const int rowTile = rowBase >> 4, colTile = colBase >> 4;

    f32x4 acc[4][8];
    #pragma unroll
    for (int i = 0; i < 4; ++i)
        #pragma unroll
        for (int j = 0; j < 8; ++j)
            #pragma unroll
            for (int r = 0; r < 4; ++r) acc[i][j][r] = 0.f;

    bf16x8 a[4];
    #pragma unroll
    for (int i = 0; i < 4; ++i)
        a[i] = *(const bf16x8*)(A0 + ((size_t)(rowTile + i) * KB + lhi) * 128 + (size_t)llo * 8);

    #pragma unroll
    for (int s = 0; s < S; ++s) {
        const short* B = (s >= KS) ? B1 : B0;
        const int kb = (s - (s >= KS ? KS : 0)) * 4 + lhi;
        bf16x8 b[8];
        #pragma unroll
        for (int j = 0; j < 8; ++j)
            b[j] = *(const bf16x8*)(B + ((size_t)(colTile + j) * KB + kb) * 128 + (size_t)llo * 8);
        bf16x8 an[4];
        if (s + 1 < S) {
            const int s1 = s + 1;
            const short* A = (s1 >= KS) ? A1 : A0;
            const int kb1 = (s1 - (s1 >= KS ? KS : 0)) * 4 + lhi;
            #pragma unroll
            for (int i = 0; i < 4; ++i)
                an[i] = *(const bf16x8*)(A + ((size_t)(rowTile + i) * KB + kb1) * 128 + (size_t)llo * 8);
        }
        #pragma unroll
        for (int i = 0; i < 4; ++i)
            #pragma unroll
            for (int j = 0; j < 8; ++j)
                acc[i][j] = __builtin_amdgcn_mfma_f32_16x16x32_bf16(a[i], b[j], acc[i][j], 0, 0, 0);
        if (s + 1 < S) {
            #pragma unroll
            for (int i = 0; i < 4; ++i) a[i] = an[i];
        }
    }

    #pragma unroll
    for (int j = 0; j < 8; ++j) {
        float bv = bias[colBase + j * 16 + llo];
        #pragma unroll
        for (int i = 0; i < 4; ++i)
            #pragma unroll
            for (int r = 0; r < 4; ++r)
                acc[i][j][r] = fmaxf(acc[i][j][r] + bv, 0.f);
    }

    #pragma unroll
    for (int half = 0; half < 2; ++half) {
        #pragma unroll
        for (int i2 = 0; i2 < 2; ++i2) {
            const int i = half * 2 + i2;
            #pragma unroll
            for (int j = 0; j < 8; ++j)
                #pragma unroll
                for (int r = 0; r < 4; ++r)
                    sC[wave][i2 * 16 + lhi * 4 + r][j * 16 + llo] = acc[i][j][r];
        }
        #pragma unroll
        for (int it = 0; it < 8; ++it) {
            const int r = it * 4 + (lane >> 4);
            const int c = (lane & 15) * 8;
            const int grow = rowBase + half * 32 + r;
            if (grow < N_NODES) {
                float4 v0 = *(const float4*)&sC[wave][r][c];
                float4 v1 = *(const float4*)&sC[wave][r][c + 4];
                __align__(16) short sv[8] = {f2bf(v0.x), f2bf(v0.y), f2bf(v0.z), f2bf(v0.w),
                                             f2bf(v1.x), f2bf(v1.y), f2bf(v1.z), f2bf(v1.w)};
                size_t pidx = ((size_t)(grow >> 4) * 32 + ((colBase + c) >> 3)) * 128
                            + (size_t)(grow & 15) * 8;
                *(int4*)(opack + pidx) = *(const int4*)sv;
            }
        }
    }
}

// ---------------- layer-2 dual-output GEMM: p = A@B0 (bf16 rows); q = A@B1 + bias (f32) ----------------
// wave tile 64 rows x 64 cols of BOTH outputs; grid (NPAD/256, 2). K = 256.
__global__ __launch_bounds__(256)
void gemm2_kernel(const short* __restrict__ A, const short* __restrict__ B0,
                  const short* __restrict__ B1, const float* __restrict__ bias,
                  short* __restrict__ prow, float* __restrict__ qf32) {
    constexpr int KB = 32, S = 8;
    __shared__ float sC[4][32][68];
    const int tid = threadIdx.x, wave = tid >> 6, lane = tid & 63;
    const int lhi = lane >> 4, llo = lane & 15;
    const int rowBase = blockIdx.x * 256 + wave * 64;
    const int colBase = blockIdx.y * 64;
    const int rowTile = rowBase >> 4, colTile = colBase >> 4;

    f32x4 accp[4][4], accq[4][4];
    #pragma unroll
    for (int i = 0; i < 4; ++i)
        #pragma unroll
        for (int j = 0; j < 4; ++j)
            #pragma unroll
            for (int r = 0; r < 4; ++r) { accp[i][j][r] = 0.f; accq[i][j][r] = 0.f; }

    bf16x8 a[4];
    #pragma unroll
    for (int i = 0; i < 4; ++i)
        a[i] = *(const bf16x8*)(A + ((size_t)(rowTile + i) * KB + lhi) * 128 + (size_t)llo * 8);

    #pragma unroll
    for (int s = 0; s < S; ++s) {
        const int kb = s * 4 + lhi;
        bf16x8 b0[4], b1[4];
        #pragma unroll
        for (int j = 0; j < 4; ++j) {
            b0[j] = *(const bf16x8*)(B0 + ((size_t)(colTile + j) * KB + kb) * 128 + (size_t)llo * 8);
            b1[j] = *(const bf16x8*)(B1 + ((size_t)(colTile + j) * KB + kb) * 128 + (size_t)llo * 8);
        }
        bf16x8 an[4];
        if (s + 1 < S) {
            const int kb1 = (s + 1) * 4 + lhi;
            #pragma unroll
            for (int i = 0; i < 4; ++i)
                an[i] = *(const bf16x8*)(A + ((size_t)(rowTile + i) * KB + kb1) * 128 + (size_t)llo * 8);
        }
        #pragma unroll
        for (int i = 0; i < 4; ++i)
            #pragma unroll
            for (int j = 0; j < 4; ++j) {
                accp[i][j] = __builtin_amdgcn_mfma_f32_16x16x32_bf16(a[i], b0[j], accp[i][j], 0, 0, 0);
                accq[i][j] = __builtin_amdgcn_mfma_f32_16x16x32_bf16(a[i], b1[j], accq[i][j], 0, 0, 0);
            }
        if (s + 1 < S) {
            #pragma unroll
            for (int i = 0; i < 4; ++i) a[i] = an[i];
        }
    }

    // p epilogue: bf16 row-major
    #pragma unroll
    for (int half = 0; half < 2; ++half) {
        #pragma unroll
        for (int i2 = 0; i2 < 2; ++i2) {
            const int i = half * 2 + i2;
            #pragma unroll
            for (int j = 0; j < 4; ++j)
                #pragma unroll
                for (int r = 0; r < 4; ++r)
                    sC[wave][i2 * 16 + lhi * 4 + r][j * 16 + llo] = accp[i][j][r];
        }
        #pragma unroll
        for (int it = 0; it < 4; ++it) {
            const int r = it * 8 + (lane >> 3);
            const int c = (lane & 7) * 8;
            const int grow = rowBase + half * 32 + r;
            if (grow < N_NODES) {
                float4 v0 = *(const float4*)&sC[wave][r][c];
                float4 v1 = *(const float4*)&sC[wave][r][c + 4];
                __align__(16) short sv[8] = {f2bf(v0.x), f2bf(v0.y), f2bf(v0.z), f2bf(v0.w),
                                             f2bf(v1.x), f2bf(v1.y), f2bf(v1.z), f2bf(v1.w)};
                *(int4*)(prow + (size_t)grow * 128 + colBase + c) = *(const int4*)sv;
            }
        }
    }

    // q epilogue: f32 + bias
    #pragma unroll
    for (int j = 0; j < 4; ++j) {
        float bv = bias[colBase + j * 16 + llo];
        #pragma unroll
        for (int i = 0; i < 4; ++i)
            #pragma unroll
            for (int r = 0; r < 4; ++r) accq[i][j][r] += bv;
    }
    #pragma unroll
    for (int half = 0; half < 2; ++half) {
        #pragma unroll
        for (int i2 = 0; i2 < 2; ++i2) {
            const int i = half * 2 + i2;
            #pragma unroll
            for (int j = 0; j < 4; ++j)
                #pragma unroll
                for (int r = 0; r < 4; ++r)
                    sC[wave][i2 * 16 + lhi * 4 + r][j * 16 + llo] = accq[i][j][r];
        }
        #pragma unroll
        for (int it = 0; it < 4; ++it) {
            const int r = it * 8 + (lane >> 3);
            const int c = (lane & 7) * 8;
            const int grow = rowBase + half * 32 + r;
            if (grow < N_NODES) {
                float4 v0 = *(const float4*)&sC[wave][r][c];
                float4 v1 = *(const float4*)&sC[wave][r][c + 4];
                *(float4*)(qf32 + (size_t)grow * 128 + colBase + c) = v0;
                *(float4*)(qf32 + (size_t)grow * 128 + colBase + c + 4) = v1;
            }
        }
    }
}

extern "C" void kernel_launch(void* const* d_in, const int* in_sizes, int n_in,
                              void* d_out, int out_size, void* d_ws, size_t ws_size,
                              hipStream_t stream) {
    const float* x   = (const float*)d_in[0];
    const int*   ei  = (const int*)d_in[1];
    const float* Wl1 = (const float*)d_in[2];
    const float* b1  = (const float*)d_in[3];
    const float* Wr1 = (const float*)d_in[4];
    const float* Wl2 = (const float*)d_in[5];
    const float* b2  = (const float*)d_in[6];
    const float* Wr2 = (const float*)d_in[7];
    const int E = in_sizes[1] / 2;
    const int* src = ei;
    const int* dst = ei + E;

    // workspace layout
    short* h_pack = (short*)d_ws;                   // NPAD*256
    short* agg1p  = h_pack + (size_t)NPAD * 256;    // NPAD*128
    short* x_row  = agg1p  + (size_t)NPAD * 128;    // NPAD*128
    short* x_pack = x_row  + (size_t)NPAD * 128;    // NPAD*128
    short* p_row  = x_pack + (size_t)NPAD * 128;    // NPAD*128
    short* wl1p   = p_row  + (size_t)NPAD * 128;    // 32768
    short* wr1p   = wl1p + 32768;
    short* wl2p   = wr1p + 32768;
    short* wr2p   = wl2p + 32768;
    int* bucket_cnt    = (int*)(wr2p + 32768);      // NBLK+1
    int* bucket_base   = bucket_cnt + NBLK + 1;     // NBLK+1
    int* bucket_cursor = bucket_base + NBLK + 1;    // NBLK+1
    int* offsets       = bucket_cursor + NBLK + 1;  // N+1
    unsigned int* bin  = (unsigned int*)(offsets + N_NODES + 1); // E
    int* sorted        = (int*)(bin + E);           // E

    const int nbin = (E + 4095) / 4096;

    // CSR build (binned two-pass counting sort)
    hipMemsetAsync(bucket_cnt, 0, (NBLK + 1) * sizeof(int), stream);
    cbuck_kernel<<<nbin, 256, 0, stream>>>(dst, bucket_cnt, E);
    scan391_kernel<<<1, 512, 0, stream>>>(bucket_cnt, bucket_base, bucket_cursor, offsets);
    bin_kernel<<<nbin, 256, 0, stream>>>(src, dst, bucket_cursor, bin, E);
    place_kernel<<<NBLK, 256, 0, stream>>>(bin, bucket_base, offsets, sorted);

    // bf16 conversions / packing
    cast_x_kernel<<<(N_NODES * 16 + 255) / 256, 256, 0, stream>>>(x, x_row, x_pack);
    pack_w_kernel<<<128, 256, 0, stream>>>(Wl1, wl1p, 128, 256);
    pack_w_kernel<<<128, 256, 0, stream>>>(Wr1, wr1p, 128, 256);
    pack_w_kernel<<<128, 256, 0, stream>>>(Wl2, wl2p, 256, 128);
    pack_w_kernel<<<128, 256, 0, stream>>>(Wr2, wr2p, 256, 128);

    // layer 1: agg(x) -> h = relu([mean,x]@[Wl1;Wr1] + b1) (packed)
    aggregate128_kernel<0><<<N_NODES / 4, 256, 0, stream>>>(x_row, offsets, sorted, agg1p, nullptr);
    gemm1_kernel<<<dim3(NPAD / 256, 2), 256, 0, stream>>>(agg1p, x_pack, wl1p, wr1p, b1, h_pack);

    // layer 2 (commuted): p = h@Wl2; q = h@Wr2 + b2 -> d_out; d_out += mean(p)
    gemm2_kernel<<<dim3(NPAD / 256, 2), 256, 0, stream>>>(h_pack, wl2p, wr2p, b2, p_row, (float*)d_out);
    aggregate128_kernel<1><<<N_NODES / 4, 256, 0, stream>>>(p_row, offsets, sorted, nullptr, (float*)d_out);
}